// Round 7
// baseline (343.593 us; speedup 1.0000x reference)
//
#include <hip/hip_runtime.h>
#include <hip/hip_bf16.h>

typedef __attribute__((ext_vector_type(8))) short short8;
typedef __attribute__((ext_vector_type(4))) float floatx4;
typedef __attribute__((ext_vector_type(4))) unsigned uint4v;

#define B_ 8
#define C_IN 256
#define C_OUT 256
#define H_ 128
#define W_ 128
#define S_ 512
#define HW_ (H_*W_)
#define LIN_SCALE 0.04419417382415922f   /* 1/sqrt(512) */
#define CONV_SCALE 0.02083333333333333f  /* 1/sqrt(256*9) */
#define EPS_ 1e-8f

#define XPH 130          /* padded H: rows -1..128 -> 0..129 */
#define XPW 136          /* padded W: cols -1..134 -> 0..135 */
#define TTH 8            /* output tile 8h x 32w = 256 px (full 128B out lines) */
#define TTW 32
#define PH2 10           /* halo patch 10 x 34 */
#define PW2 34
#define NPIX2 (PH2*PW2)  /* 340 */
#define NITEM2 (NPIX2*4) /* 1360 16B-items per ci-chunk */
#define BUFSZ (NITEM2*16) /* 21760 B per LDS buffer */
#define NKB 72           /* 8 ci-chunks * 9 taps */
#define NTHR 256         /* 4 waves: 2(M) x 2(N) */

__device__ __forceinline__ unsigned short f2bf(float f) {
  unsigned u = __builtin_bit_cast(unsigned, f);
  u = (u + 0x7fffu + ((u >> 16) & 1u)) >> 16;
  return (unsigned short)u;
}
__device__ __forceinline__ unsigned pack2(float a, float b) {
  return (unsigned)f2bf(a) | ((unsigned)f2bf(b) << 16);
}
__device__ __forceinline__ void gload16(const void* g, void* l) {
  __builtin_amdgcn_global_load_lds(
      (const __attribute__((address_space(1))) unsigned*)g,
      (__attribute__((address_space(3))) unsigned*)l, 16, 0, 0);
}

// ---------------- kernel 1: style modulation s[b][ci] ----------------
__global__ void k_style(const float* __restrict__ style, const float* __restrict__ mw,
                        const float* __restrict__ mb, float* __restrict__ s) {
  __shared__ float sty[S_];
  const int b = blockIdx.x;
  for (int i = threadIdx.x; i < S_; i += 256) sty[i] = style[b*S_ + i];
  __syncthreads();
  const int ci = threadIdx.x;  // 256 threads
  const float* wr = mw + (size_t)ci*S_;
  float acc = 0.f;
  for (int i = 0; i < S_; ++i) acc += sty[i] * wr[i];
  s[b*C_IN + ci] = acc * LIN_SCALE + mb[ci];
}

// ---------------- kernel 2: demod[b][co] ----------------
__global__ void k_demod(const float* __restrict__ weight, const float* __restrict__ s,
                        float* __restrict__ demod) {
  const int b = blockIdx.x >> 8, co = blockIdx.x & 255;
  const int l = threadIdx.x;  // 64 threads
  const float* wrow = weight + (size_t)co*C_IN*9;
  const float* sb = s + b*C_IN;
  float acc = 0.f;
  for (int idx = l; idx < C_IN*9; idx += 64) {
    float wv = wrow[idx] * sb[idx/9];
    acc += wv*wv;
  }
#pragma unroll
  for (int off = 32; off; off >>= 1) acc += __shfl_down(acc, off, 64);
  if (l == 0) demod[blockIdx.x] = rsqrtf(acc * (CONV_SCALE*CONV_SCALE) + EPS_);
}

// ---------------- kernel 3: pack modulated weights into MFMA A-fragment order ----------------
// layout: frag[((b*72 + kb)*16 + mt)*64 + lane][8] bf16, kb = ci_chunk*9 + tap
// A-frag lane l: co = mt*16 + (l&15), k_in = (l>>4)*8 + j, ci = chunk*32 + k_in
__global__ void k_pack(const float* __restrict__ weight, const float* __restrict__ s,
                       const float* __restrict__ demod, unsigned short* __restrict__ frag) {
  const int bid = blockIdx.x;            // (b*72 + kb)*16 + mt
  const int mt = bid & 15;
  const int kb = (bid >> 4) % NKB;
  const int b  = bid / (NKB*16);
  const int l = threadIdx.x;             // 64 threads
  const int co = mt*16 + (l & 15);
  const int chunk = kb / 9, r = kb % 9;
  const float dm = demod[b*C_OUT + co] * CONV_SCALE;
  const float* sb = s + b*C_IN;
  unsigned v[4];
#pragma unroll
  for (int jj = 0; jj < 4; ++jj) {
    int ci0 = chunk*32 + (l >> 4)*8 + jj*2;
    unsigned lo = f2bf(weight[((size_t)co*C_IN + ci0    )*9 + r] * sb[ci0    ] * dm);
    unsigned hi = f2bf(weight[((size_t)co*C_IN + ci0 + 1)*9 + r] * sb[ci0 + 1] * dm);
    v[jj] = lo | (hi << 16);
  }
  unsigned* dst = (unsigned*)(frag + (size_t)bid*512 + l*8);
  dst[0] = v[0]; dst[1] = v[1]; dst[2] = v[2]; dst[3] = v[3];
}

// ---------------- kernel 3b: zero only the read border of xpad ----------------
// conv reads rows 0..129, cols 0..129 of each (b,c) plane; k_xpose writes the
// interior (1..128 x 1..128). Zero row 0, row 129, col 0, col 129 only.
__global__ void k_border(unsigned short* __restrict__ xp) {
  const int plane = blockIdx.x;          // b*8 + c, 64 planes
  unsigned short* base = xp + (size_t)plane*XPH*XPW*32;
  const uint4v z = {0u,0u,0u,0u};
  for (int i = threadIdx.x; i < 516; i += 256) {
    int hh, ww;
    if (i < 260) { hh = (i < 130) ? 0 : 129; ww = i % 130; }
    else { int j = i - 260; ww = (j < 128) ? 0 : 129; hh = 1 + (j & 127); }
    uint4v* p = (uint4v*)(base + ((size_t)hh*XPW + ww)*32);
    p[0] = z; p[1] = z; p[2] = z; p[3] = z;
  }
}

// ---------------- kernel 3c: NCHW f32 -> chunk-major padded bf16 ----------------
// xpad[b][c][hh][ww][32ci] bf16, c = ci-chunk (8), hh = h+1, ww = w+1.
__global__ void k_xpose(const float* __restrict__ x, unsigned short* __restrict__ xp) {
  __shared__ __align__(16) unsigned lds32[64*128];   // 32 KB
  const int bid = blockIdx.x;          // 8b * 128h * 2
  const int half = bid & 1, h = (bid >> 1) & 127, b = bid >> 8;
  const int w0 = half*64;
  const int t = threadIdx.x;
  const float* xr = x + (size_t)b*C_IN*HW_ + (size_t)h*W_ + w0;
#pragma unroll
  for (int j = 0; j < 8; ++j) {
    int cp = j*16 + (t >> 4);          // ci-pair 0..127
    int ci = cp*2;
    const float* p0 = xr + (size_t)ci*HW_ + (t & 15)*4;
    floatx4 f0 = *(const floatx4*)p0;
    floatx4 f1 = *(const floatx4*)(p0 + HW_);
    int g = cp >> 2, slot = cp & 3;
#pragma unroll
    for (int k = 0; k < 4; ++k) {
      int px = (t & 15)*4 + k;
      lds32[px*128 + ((g ^ ((px >> 2) & 7)) << 2) + slot] = pack2(f0[k], f1[k]);
    }
  }
  __syncthreads();
#pragma unroll
  for (int i = 0; i < 8; ++i) {
    int item = i*256 + t;
    int px = item >> 5, g = item & 31;       // g = 8-ci group = (c<<2)|sub
    int c = (item >> 2) & 7, sub = item & 3;
    int gs = g ^ ((px >> 2) & 7);
    uint4v v = *(const uint4v*)&lds32[px*128 + (gs << 2)];
    unsigned short* dst = xp +
        (((size_t)(b*8 + c)*XPH + (h + 1))*XPW + (w0 + 1 + px))*32 + sub*8;
    *(uint4v*)dst = v;
  }
}

// ---------------- kernel 4: implicit-GEMM conv ----------------
// block: 128 co (ct half) x (8h x 32w = 256 px), 256 threads, 4 waves 2(M)x2(N)
// wave tile: 64 co x 128 px = 4(m) x 8(n) frags of 16x16; acc = 128 AGPR.
// Schedule (T3/T4/T5): 3 LDS buffers; stage(c+2) issued at END of chunk c
// (after all of chunk c's A-loads -> no A-wait drains it until next chunk's
// step2, ~2.5 steps of margin); raw s_barrier with counted vmcnt(14)
// (= pa+pb prefetch(8) + stage(c+2)(6) stay in flight across the barrier);
// 3-deep pa/pb/pc A-rotation (loadA r+2 while computing r).
__launch_bounds__(NTHR, 2)
__global__ void k_conv(const unsigned short* __restrict__ xpad,
                       const unsigned short* __restrict__ frag,
                       float* __restrict__ out) {
  __shared__ __align__(16) unsigned char lds[3][BUFSZ];   // 65280 B -> 2 blocks/CU
  // XCD chunk swizzle: XCD x <- batch x (frag set per XCD stays L2-hot)
  const int work = (blockIdx.x & 7)*128 + (blockIdx.x >> 3);
  const int ct = work & 1;
  const int w2 = work >> 1;
  const int sx = w2 & 3, sy = (w2 >> 2) & 15, b = w2 >> 6;
  const int h0 = sy*TTH, w0 = sx*TTW;
  const int tid = threadIdx.x;
  const int lane = tid & 63, wv = tid >> 6;
  const int wm = wv >> 1, wn = wv & 1;

  const unsigned short* fb = frag + (size_t)b*NKB*16*512 + (size_t)lane*8;

  floatx4 acc[4][8];
#pragma unroll
  for (int m = 0; m < 4; ++m)
#pragma unroll
    for (int n = 0; n < 8; ++n) acc[m][n] = floatx4{0.f, 0.f, 0.f, 0.f};

  auto stageB = [&](int c, unsigned char* buf) {
    const unsigned short* xc = xpad +
        ((size_t)((b*8 + c)*XPH + h0)*XPW + w0)*32;   // patch origin (pads cancel)
#pragma unroll
    for (int i = 0; i < 6; ++i) {
      int item = tid + i*NTHR;
      if (i < 5 || tid < (NITEM2 - 5*NTHR)) {
        int px = item >> 2, q8s = item & 3;
        int ph = px / PW2, pw = px - ph*PW2;
        int q8 = q8s ^ ((px >> 1) & 3);          // pre-swizzled SOURCE (rule #21)
        const unsigned short* src = xc + ((size_t)ph*XPW + pw)*32 + q8*8;
        gload16(src, buf + item*16);
      }
    }
  };

  short8 pa[4], pb[4], pc[4];
  auto loadA = [&](short8* dst, int kb) {
#pragma unroll
    for (int m = 0; m < 4; ++m) {
      int mt = ct*8 + wm*4 + m;
      dst[m] = *(const short8*)(fb + (size_t)(kb*16 + mt)*512);
    }
  };

  const int sl = lane >> 4, c15 = lane & 15;
  auto step = [&](const short8* A, int dh, int dw, const unsigned char* cl) {
    __builtin_amdgcn_s_setprio(1);
#pragma unroll
    for (int n = 0; n < 8; ++n) {
      int nt = wn*8 + n;                   // h = nt>>1, w-half = nt&1
      int ph = (nt >> 1) + dh;
      int pw = (nt & 1)*16 + c15 + dw;
      int pix = ph*PW2 + pw;
      int addr = pix*64 + ((sl ^ ((pix >> 1) & 3)) << 4);
      short8 bb = *(const short8*)(cl + addr);
#pragma unroll
      for (int m = 0; m < 4; ++m)
        acc[m][n] = __builtin_amdgcn_mfma_f32_16x16x32_bf16(A[m], bb, acc[m][n], 0, 0, 0);
    }
    __builtin_amdgcn_s_setprio(0);
  };

#define SBAR0 __builtin_amdgcn_sched_barrier(0)
#define RAW_BARRIER(NSTR) do { SBAR0; \
    asm volatile("s_waitcnt vmcnt(" NSTR ")" ::: "memory"); \
    __builtin_amdgcn_s_barrier(); SBAR0; } while (0)

  unsigned char* LR = lds[0];   // read buffer (chunk c)
  unsigned char* LN = lds[1];   // next read (chunk c+1, staged previously)
  unsigned char* LS = lds[2];   // stage target (chunk c+2)

  // prologue: order matters for FIFO math: stage0(6), pa(4), pb(4), stage1(6)
  stageB(0, LR);
  loadA(pa, 0);
  loadA(pb, 1);
  stageB(1, LN);
  RAW_BARRIER("6");   // oldest 14 (stage0+pa+pb) done; stage1 stays in flight

  for (int c = 0; c < 6; ++c) {
    const int K = c*9;
    loadA(pc, K + 2); step(pa, 0, 0, LR);
    loadA(pa, K + 3); step(pb, 0, 1, LR);
    loadA(pb, K + 4); step(pc, 0, 2, LR);
    loadA(pc, K + 5); step(pa, 1, 0, LR);
    loadA(pa, K + 6); step(pb, 1, 1, LR);
    loadA(pb, K + 7); step(pc, 1, 2, LR);
    loadA(pc, K + 8); step(pa, 2, 0, LR);
    loadA(pa, K + 9); step(pb, 2, 1, LR);   // next chunk r0 -> pa
    loadA(pb, K + 10); step(pc, 2, 2, LR);  // next chunk r1 -> pb
    stageB(c + 2, LS);                      // issued AFTER all A-loads of chunk c
    RAW_BARRIER("14");                      // stage(c+1) done; pa+pb+stage(c+2) in flight
    unsigned char* t = LR; LR = LN; LN = LS; LS = t;
  }
  {  // c = 6: no stage
    const int K = 54;
    loadA(pc, K + 2); step(pa, 0, 0, LR);
    loadA(pa, K + 3); step(pb, 0, 1, LR);
    loadA(pb, K + 4); step(pc, 0, 2, LR);
    loadA(pc, K + 5); step(pa, 1, 0, LR);
    loadA(pa, K + 6); step(pb, 1, 1, LR);
    loadA(pb, K + 7); step(pc, 1, 2, LR);
    loadA(pc, K + 8); step(pa, 2, 0, LR);
    loadA(pa, K + 9); step(pb, 2, 1, LR);
    loadA(pb, K + 10); step(pc, 2, 2, LR);
    RAW_BARRIER("8");                       // stage(7) done; pa+pb in flight
    LR = LN;
  }
  {  // c = 7: tail, no prefetch, no barrier
    const int K = 63;
    loadA(pc, K + 2); step(pa, 0, 0, LR);
    loadA(pa, K + 3); step(pb, 0, 1, LR);
    loadA(pb, K + 4); step(pc, 0, 2, LR);
    loadA(pc, K + 5); step(pa, 1, 0, LR);
    loadA(pa, K + 6); step(pb, 1, 1, LR);
    loadA(pb, K + 7); step(pc, 1, 2, LR);
    loadA(pc, K + 8); step(pa, 2, 0, LR);
    step(pb, 2, 1, LR);
    step(pc, 2, 2, LR);
  }

  // epilogue: C/D col=lane&15 (pixel w), row=(lane>>4)*4+i (co)
  float* ob = out + ((size_t)b*C_OUT + ct*128)*HW_;
  const int tw = lane & 15, rg = lane >> 4;
#pragma unroll
  for (int m = 0; m < 4; ++m) {
#pragma unroll
    for (int n = 0; n < 8; ++n) {
      int co = (wm*4 + m)*16 + rg*4;
      int nt = wn*8 + n;
      int h = h0 + (nt >> 1);
      int w = w0 + (nt & 1)*16 + tw;
      float* p = ob + (size_t)co*HW_ + (size_t)h*W_ + w;
#pragma unroll
      for (int i = 0; i < 4; ++i) p[i*HW_] = acc[m][n][i];
    }
  }
#undef SBAR0
#undef RAW_BARRIER
}

extern "C" void kernel_launch(void* const* d_in, const int* in_sizes, int n_in,
                              void* d_out, int out_size, void* d_ws, size_t ws_size,
                              hipStream_t stream) {
  const float* x      = (const float*)d_in[0];
  const float* style  = (const float*)d_in[1];
  const float* weight = (const float*)d_in[2];
  const float* mod_w  = (const float*)d_in[3];
  const float* mod_b  = (const float*)d_in[4];
  float* out = (float*)d_out;
  char* ws = (char*)d_ws;

  float* s     = (float*)ws;                            // 8 KB
  float* demod = (float*)(ws + 8192);                   // 8 KB
  unsigned short* frag = (unsigned short*)(ws + 16384); // 9.44 MB
  unsigned short* xpad = (unsigned short*)(ws + (16u<<20)); // 72.4 MB chunk-major bf16

  k_style<<<B_, 256, 0, stream>>>(style, mod_w, mod_b, s);
  k_demod<<<B_*C_OUT, 64, 0, stream>>>(weight, s, demod);
  k_pack<<<B_*NKB*16, 64, 0, stream>>>(weight, s, demod, frag);
  k_border<<<B_*8, 256, 0, stream>>>(xpad);
  k_xpose<<<B_*H_*2, 256, 0, stream>>>(x, xpad);
  k_conv<<<B_*2*16*4, NTHR, 0, stream>>>(xpad, frag, out);
}

// Round 9
// 258.157 us; speedup vs baseline: 1.3309x; 1.3309x over previous
//
#include <hip/hip_runtime.h>
#include <hip/hip_bf16.h>

typedef __attribute__((ext_vector_type(8))) short short8;
typedef __attribute__((ext_vector_type(4))) float floatx4;
typedef __attribute__((ext_vector_type(4))) unsigned uint4v;

#define B_ 8
#define C_IN 256
#define C_OUT 256
#define H_ 128
#define W_ 128
#define S_ 512
#define HW_ (H_*W_)
#define LIN_SCALE 0.04419417382415922f   /* 1/sqrt(512) */
#define CONV_SCALE 0.02083333333333333f  /* 1/sqrt(256*9) */
#define EPS_ 1e-8f

#define XPH 130          /* padded H: rows -1..128 -> 0..129 */
#define XPW 136          /* padded W: cols -1..134 -> 0..135 */
#define TTH 8            /* output tile 8h x 32w = 256 px (full 128B out lines) */
#define TTW 32
#define PH2 10           /* halo patch 10 x 34 */
#define PW2 34
#define NPIX2 (PH2*PW2)  /* 340 live pixels */
#define NITEM2 (NPIX2*4) /* 1360 live 16B-items per ci-chunk */
#define BITEMS 1536      /* padded to 6 exact 256-thread pieces */
#define BUFSZ (BITEMS*16) /* 24576 B per B LDS buffer (incl. pad, never read) */
#define ABUFSZ 8192       /* 8 mt-frags * 1 KB per A LDS buffer */
#define NKB 72           /* 8 ci-chunks * 9 taps */
#define NTHR 256         /* 4 waves: 2(M) x 2(N) */

__device__ __forceinline__ unsigned short f2bf(float f) {
  unsigned u = __builtin_bit_cast(unsigned, f);
  u = (u + 0x7fffu + ((u >> 16) & 1u)) >> 16;
  return (unsigned short)u;
}
__device__ __forceinline__ unsigned pack2(float a, float b) {
  return (unsigned)f2bf(a) | ((unsigned)f2bf(b) << 16);
}
__device__ __forceinline__ void gload16(const void* g, void* l) {
  __builtin_amdgcn_global_load_lds(
      (const __attribute__((address_space(1))) unsigned*)g,
      (__attribute__((address_space(3))) unsigned*)l, 16, 0, 0);
}

// ---------------- kernel 1: style modulation s[b][ci] ----------------
__global__ void k_style(const float* __restrict__ style, const float* __restrict__ mw,
                        const float* __restrict__ mb, float* __restrict__ s) {
  __shared__ float sty[S_];
  const int b = blockIdx.x;
  for (int i = threadIdx.x; i < S_; i += 256) sty[i] = style[b*S_ + i];
  __syncthreads();
  const int ci = threadIdx.x;  // 256 threads
  const float* wr = mw + (size_t)ci*S_;
  float acc = 0.f;
  for (int i = 0; i < S_; ++i) acc += sty[i] * wr[i];
  s[b*C_IN + ci] = acc * LIN_SCALE + mb[ci];
}

// ---------------- kernel 2: demod[b][co] ----------------
__global__ void k_demod(const float* __restrict__ weight, const float* __restrict__ s,
                        float* __restrict__ demod) {
  const int b = blockIdx.x >> 8, co = blockIdx.x & 255;
  const int l = threadIdx.x;  // 64 threads
  const float* wrow = weight + (size_t)co*C_IN*9;
  const float* sb = s + b*C_IN;
  float acc = 0.f;
  for (int idx = l; idx < C_IN*9; idx += 64) {
    float wv = wrow[idx] * sb[idx/9];
    acc += wv*wv;
  }
#pragma unroll
  for (int off = 32; off; off >>= 1) acc += __shfl_down(acc, off, 64);
  if (l == 0) demod[blockIdx.x] = rsqrtf(acc * (CONV_SCALE*CONV_SCALE) + EPS_);
}

// ---------------- kernel 3: pack modulated weights into MFMA A-fragment order ----------------
// layout: frag[((b*72 + kb)*16 + mt)*64 + lane][8] bf16, kb = ci_chunk*9 + tap
// A-frag lane l: co = mt*16 + (l&15), k_in = (l>>4)*8 + j, ci = chunk*32 + k_in
__global__ void k_pack(const float* __restrict__ weight, const float* __restrict__ s,
                       const float* __restrict__ demod, unsigned short* __restrict__ frag) {
  const int bid = blockIdx.x;            // (b*72 + kb)*16 + mt
  const int mt = bid & 15;
  const int kb = (bid >> 4) % NKB;
  const int b  = bid / (NKB*16);
  const int l = threadIdx.x;             // 64 threads
  const int co = mt*16 + (l & 15);
  const int chunk = kb / 9, r = kb % 9;
  const float dm = demod[b*C_OUT + co] * CONV_SCALE;
  const float* sb = s + b*C_IN;
  unsigned v[4];
#pragma unroll
  for (int jj = 0; jj < 4; ++jj) {
    int ci0 = chunk*32 + (l >> 4)*8 + jj*2;
    unsigned lo = f2bf(weight[((size_t)co*C_IN + ci0    )*9 + r] * sb[ci0    ] * dm);
    unsigned hi = f2bf(weight[((size_t)co*C_IN + ci0 + 1)*9 + r] * sb[ci0 + 1] * dm);
    v[jj] = lo | (hi << 16);
  }
  unsigned* dst = (unsigned*)(frag + (size_t)bid*512 + l*8);
  dst[0] = v[0]; dst[1] = v[1]; dst[2] = v[2]; dst[3] = v[3];
}

// ---------------- kernel 3b: zero only the read border of xpad ----------------
__global__ void k_border(unsigned short* __restrict__ xp) {
  const int plane = blockIdx.x;          // b*8 + c, 64 planes
  unsigned short* base = xp + (size_t)plane*XPH*XPW*32;
  const uint4v z = {0u,0u,0u,0u};
  for (int i = threadIdx.x; i < 516; i += 256) {
    int hh, ww;
    if (i < 260) { hh = (i < 130) ? 0 : 129; ww = i % 130; }
    else { int j = i - 260; ww = (j < 128) ? 0 : 129; hh = 1 + (j & 127); }
    uint4v* p = (uint4v*)(base + ((size_t)hh*XPW + ww)*32);
    p[0] = z; p[1] = z; p[2] = z; p[3] = z;
  }
}

// ---------------- kernel 3c: NCHW f32 -> chunk-major padded bf16 ----------------
// xpad[b][c][hh][ww][32ci] bf16, c = ci-chunk (8), hh = h+1, ww = w+1.
__global__ void k_xpose(const float* __restrict__ x, unsigned short* __restrict__ xp) {
  __shared__ __align__(16) unsigned lds32[64*128];   // 32 KB
  const int bid = blockIdx.x;          // 8b * 128h * 2
  const int half = bid & 1, h = (bid >> 1) & 127, b = bid >> 8;
  const int w0 = half*64;
  const int t = threadIdx.x;
  const float* xr = x + (size_t)b*C_IN*HW_ + (size_t)h*W_ + w0;
#pragma unroll
  for (int j = 0; j < 8; ++j) {
    int cp = j*16 + (t >> 4);          // ci-pair 0..127
    int ci = cp*2;
    const float* p0 = xr + (size_t)ci*HW_ + (t & 15)*4;
    floatx4 f0 = *(const floatx4*)p0;
    floatx4 f1 = *(const floatx4*)(p0 + HW_);
    int g = cp >> 2, slot = cp & 3;
#pragma unroll
    for (int k = 0; k < 4; ++k) {
      int px = (t & 15)*4 + k;
      lds32[px*128 + ((g ^ ((px >> 2) & 7)) << 2) + slot] = pack2(f0[k], f1[k]);
    }
  }
  __syncthreads();
#pragma unroll
  for (int i = 0; i < 8; ++i) {
    int item = i*256 + t;
    int px = item >> 5, g = item & 31;       // g = 8-ci group = (c<<2)|sub
    int c = (item >> 2) & 7, sub = item & 3;
    int gs = g ^ ((px >> 2) & 7);
    uint4v v = *(const uint4v*)&lds32[px*128 + (gs << 2)];
    unsigned short* dst = xp +
        (((size_t)(b*8 + c)*XPH + (h + 1))*XPW + (w0 + 1 + px))*32 + sub*8;
    *(uint4v*)dst = v;
  }
}

// ---------------- kernel 4: implicit-GEMM conv ----------------
// Invariant (m97/m201): NO global load feeds MFMA; A and B both go
// global -> LDS (async gload_lds) -> ds_read. One raw s_barrier per step with
// exact counted vmcnt (issues AFTER the barrier, compute before the next).
// A: 3 buffers (8 KB), staged 2 steps ahead; s%3 == r%3 so buffer choice is
// compile-time. B: 2 padded buffers (1536 items), 1 full 256-thread piece per
// step. EVERY gload_lds has a LINEAR LDS dest (item*16 / tid*16): rule #21 —
// the HW writes wave-uniform base + lane*16; round-8's clamped dest made
// clamped waves stream 64 lanes past the buffer (the absmax-51 bug). Pad
// items clamp only the SOURCE px and land in the never-read pad region.
// Uniform loads/wave (A:2, B:1) make the counted-vmcnt table exact per wave.
__launch_bounds__(NTHR, 2)
__global__ void k_conv(const unsigned short* __restrict__ xpad,
                       const unsigned short* __restrict__ frag,
                       float* __restrict__ out) {
  __shared__ __align__(16) unsigned char sm[2*BUFSZ + 3*ABUFSZ];  // 73728 B
  unsigned char* b0  = sm;
  unsigned char* b1  = sm + BUFSZ;
  unsigned char* ab0 = sm + 2*BUFSZ;
  unsigned char* ab1 = ab0 + ABUFSZ;
  unsigned char* ab2 = ab1 + ABUFSZ;
  unsigned char* abv[3] = {ab0, ab1, ab2};   // indexed by compile-time consts only

  const int work = (blockIdx.x & 7)*128 + (blockIdx.x >> 3);  // XCD x <- batch x
  const int ct = work & 1;
  const int w2 = work >> 1;
  const int sx = w2 & 3, sy = (w2 >> 2) & 15, b = w2 >> 6;
  const int h0 = sy*TTH, w0 = sx*TTW;
  const int tid = threadIdx.x;
  const int lane = tid & 63, wv = tid >> 6;
  const int wm = wv >> 1, wn = wv & 1;
  const int sl = lane >> 4, c15 = lane & 15, wn8 = wn*8;

  floatx4 acc[4][8];
#pragma unroll
  for (int m = 0; m < 4; ++m)
#pragma unroll
    for (int n = 0; n < 8; ++n) acc[m][n] = floatx4{0.f, 0.f, 0.f, 0.f};

  // A-stage: kb-slice (this ct half, 8 KB) -> abv[kb%3]; 2 gloads/thread,
  // linear dest tid*16 (wave base = ab + wv*1024, lane stride 16 ✓).
  auto stageA = [&](int kb, unsigned char* ab) {
    const unsigned short* src = frag +
        ((size_t)((b*NKB + kb)*16 + ct*8))*512 + (size_t)tid*8;
    gload16(src,        ab + tid*16);
    gload16(src + 2048, ab + 4096 + tid*16);
  };
  // B-stage piece: 1 gload/thread, ALWAYS issued, linear dest item*16;
  // pad items (px >= 340) read a clamped source and land in the pad tail.
  auto stageBpiece = [&](int cSrc, int piece, unsigned char* bbf) {
    int item = piece*256 + tid;
    int px = item >> 2, q8s = item & 3;
    if (px > NPIX2 - 1) px = NPIX2 - 1;      // SOURCE clamp only; dest stays linear
    int ph = px / PW2, pw = px - ph*PW2;
    int q8 = q8s ^ ((px >> 1) & 3);          // pre-swizzled SOURCE (rule #21)
    const unsigned short* src = xpad +
        (((size_t)(b*8 + cSrc)*XPH + h0 + ph)*XPW + (w0 + pw))*32 + q8*8;
    gload16(src, bbf + item*16);
  };

  auto computeStep = [&](int dh, int dw, const unsigned char* ar,
                         const unsigned char* bc) __attribute__((always_inline)) {
    __builtin_amdgcn_s_setprio(1);
    short8 A0 = *(const short8*)(ar + (wm*4 + 0)*1024 + lane*16);
    short8 A1 = *(const short8*)(ar + (wm*4 + 1)*1024 + lane*16);
    short8 A2 = *(const short8*)(ar + (wm*4 + 2)*1024 + lane*16);
    short8 A3 = *(const short8*)(ar + (wm*4 + 3)*1024 + lane*16);
#pragma unroll
    for (int n = 0; n < 8; ++n) {
      int nt = wn8 + n;
      int pix = ((nt >> 1) + dh)*PW2 + ((nt & 1)*16 + c15 + dw);
      int addr = pix*64 + ((sl ^ ((pix >> 1) & 3)) << 4);
      short8 bb = *(const short8*)(bc + addr);
      acc[0][n] = __builtin_amdgcn_mfma_f32_16x16x32_bf16(A0, bb, acc[0][n], 0, 0, 0);
      acc[1][n] = __builtin_amdgcn_mfma_f32_16x16x32_bf16(A1, bb, acc[1][n], 0, 0, 0);
      acc[2][n] = __builtin_amdgcn_mfma_f32_16x16x32_bf16(A2, bb, acc[2][n], 0, 0, 0);
      acc[3][n] = __builtin_amdgcn_mfma_f32_16x16x32_bf16(A3, bb, acc[3][n], 0, 0, 0);
    }
    __builtin_amdgcn_s_setprio(0);
  };

#define SBAR0 __builtin_amdgcn_sched_barrier(0)
#define WAITB(NLIT) do { SBAR0; \
    asm volatile("s_waitcnt vmcnt(" NLIT ")" ::: "memory"); \
    __builtin_amdgcn_s_barrier(); SBAR0; } while (0)

// main-loop step (chunks 0..6): issue A(s+2), B piece r -> next chunk
#define STEPM(R, NLIT) do { \
    WAITB(NLIT); \
    stageA(c9 + (R) + 2, abv[((R) + 2) % 3]); \
    if ((R) < 6) stageBpiece(c + 1, (R), bs); \
    computeStep((R)/3, (R)%3, abv[(R) % 3], bc); \
  } while (0)
// last chunk (c=7): no B staging; A up to kb=71
#define STEP7(R, NLIT) do { \
    WAITB(NLIT); \
    if ((R) < 7) stageA(63 + (R) + 2, abv[((R) + 2) % 3]); \
    computeStep((R)/3, (R)%3, abv[(R) % 3], bc); \
  } while (0)

  // prologue: B chunk0 (6 pieces), A(0), A(1); full drain once.
  for (int i = 0; i < 6; ++i) stageBpiece(0, i, b0);
  stageA(0, ab0);
  stageA(1, ab1);
  SBAR0;
  asm volatile("s_waitcnt vmcnt(0)" ::: "memory");
  __builtin_amdgcn_s_barrier();
  SBAR0;

  for (int c = 0; c < 7; ++c) {
    const int c9 = c*9;
    unsigned char* bc = (c & 1) ? b1 : b0;
    unsigned char* bs = (c & 1) ? b0 : b1;
    STEPM(0, "2"); STEPM(1, "3"); STEPM(2, "4");
    STEPM(3, "4"); STEPM(4, "4"); STEPM(5, "4");
    STEPM(6, "4"); STEPM(7, "3"); STEPM(8, "2");
  }
  {
    unsigned char* bc = b1;   // chunk 7 reads b1
    STEP7(0, "2"); STEP7(1, "2"); STEP7(2, "2");
    STEP7(3, "2"); STEP7(4, "2"); STEP7(5, "2");
    STEP7(6, "2"); STEP7(7, "2"); STEP7(8, "0");
  }
#undef STEPM
#undef STEP7
#undef WAITB
#undef SBAR0

  // epilogue: C/D col=lane&15 (pixel w), row=(lane>>4)*4+i (co)
  float* ob = out + ((size_t)b*C_OUT + ct*128)*HW_;
  const int tw = lane & 15, rg = lane >> 4;
#pragma unroll
  for (int m = 0; m < 4; ++m) {
#pragma unroll
    for (int n = 0; n < 8; ++n) {
      int co = (wm*4 + m)*16 + rg*4;
      int nt = wn8 + n;
      int h = h0 + (nt >> 1);
      int w = w0 + (nt & 1)*16 + tw;
      float* p = ob + (size_t)co*HW_ + (size_t)h*W_ + w;
#pragma unroll
      for (int i = 0; i < 4; ++i) p[i*HW_] = acc[m][n][i];
    }
  }
}

extern "C" void kernel_launch(void* const* d_in, const int* in_sizes, int n_in,
                              void* d_out, int out_size, void* d_ws, size_t ws_size,
                              hipStream_t stream) {
  const float* x      = (const float*)d_in[0];
  const float* style  = (const float*)d_in[1];
  const float* weight = (const float*)d_in[2];
  const float* mod_w  = (const float*)d_in[3];
  const float* mod_b  = (const float*)d_in[4];
  float* out = (float*)d_out;
  char* ws = (char*)d_ws;

  float* s     = (float*)ws;                            // 8 KB
  float* demod = (float*)(ws + 8192);                   // 8 KB
  unsigned short* frag = (unsigned short*)(ws + 16384); // 9.44 MB
  unsigned short* xpad = (unsigned short*)(ws + (16u<<20)); // 72.4 MB chunk-major bf16

  k_style<<<B_, 256, 0, stream>>>(style, mod_w, mod_b, s);
  k_demod<<<B_*C_OUT, 64, 0, stream>>>(weight, s, demod);
  k_pack<<<B_*NKB*16, 64, 0, stream>>>(weight, s, demod, frag);
  k_border<<<B_*8, 256, 0, stream>>>(xpad);
  k_xpose<<<B_*H_*2, 256, 0, stream>>>(x, xpad);
  k_conv<<<B_*2*16*4, NTHR, 0, stream>>>(xpad, frag, out);
}